// Round 6
// baseline (289.431 us; speedup 1.0000x reference)
//
#include <hip/hip_runtime.h>

// MHA forward, MI355X gfx950. B=4 D=1024 S=2048 H=16 hd=64.
// R5: attn — P LDS round-trip ELIMINATED. S^T C-layout (lane: col q=rl, rows
// key=quad*4+r) is bit-exact the B-operand layout of v_mfma 16x16x16 (k=quad*4+j),
// so PV runs as O^T = V^T * P^T with P^T fed straight from registers
// (exp+cvt in-place). V^T A-fragments are b64 reads from the SAME swizzled LDS
// layout already staged. l = packed f32x4 VALU accumulation (2 shuffles at end).
// LDS/block 64->32 KB, no mid lgkm wait, grid back to (bh, qtile) for XCD/L2
// locality (R3: FETCH 37 MB vs 139 MB).

typedef __bf16 bf16;
typedef __attribute__((ext_vector_type(8))) __bf16 bf16x8;
typedef __attribute__((ext_vector_type(4))) __bf16 bf16x4;
typedef __attribute__((ext_vector_type(4))) float f32x4;
typedef __attribute__((ext_vector_type(4))) short s16x4;

#define NB 4
#define ND 1024
#define NS 2048
#define NH 16
#define NM 8192  // NB*NS

__device__ __forceinline__ void gld16(const void* g, void* l) {
  __builtin_amdgcn_global_load_lds((__attribute__((address_space(1))) void*)g,
                                   (__attribute__((address_space(3))) void*)l, 16, 0, 0);
}

__device__ __forceinline__ int swz4(int r) { return (r + (r >> 2)) & 3; }

__device__ __forceinline__ float exp2_fast(float x) {
#if __has_builtin(__builtin_amdgcn_exp2f)
  return __builtin_amdgcn_exp2f(x);
#else
  return exp2f(x);
#endif
}

// ===================== prep_x: xT[b*S+s][d] = bf16(x[b][d][s] + PE[d][s]) ===
__global__ __launch_bounds__(256) void prep_x_kernel(const float* __restrict__ x,
                                                     bf16* __restrict__ xT) {
  __shared__ float t[32][33];
  const int tx = threadIdx.x, ty = threadIdx.y;
  const int s0 = blockIdx.x * 32, d0 = blockIdx.y * 32, b = blockIdx.z;
#pragma unroll
  for (int i = 0; i < 4; ++i) {
    const int rr = ty + i * 8;
    const int d = d0 + rr, s = s0 + tx;
    const float freq = __expf(-(float)(d >> 1) * 0.01798894603980689f);
    const float ang = (float)s * freq;
    const float pe = (d & 1) ? cosf(ang) : sinf(ang);  // precise: ang up to 2047 rad
    t[rr][tx] = x[((size_t)b * ND + d) * NS + s] + pe;
  }
  __syncthreads();
#pragma unroll
  for (int i = 0; i < 4; ++i) {
    const int a = ty + i * 8;  // s offset
    xT[((size_t)b * NS + s0 + a) * ND + d0 + tx] = (bf16)t[tx][a];
  }
}

// ===================== prep_w: Wq|Wk|Wv -> Wqkv bf16 [3072][1024]; Wo -> bf16
__global__ __launch_bounds__(256) void prep_w_kernel(const float* __restrict__ Wq,
                                                     const float* __restrict__ Wk,
                                                     const float* __restrict__ Wv,
                                                     const float* __restrict__ Wo,
                                                     bf16* __restrict__ Wqkv,
                                                     bf16* __restrict__ WoB) {
  const size_t t = (size_t)blockIdx.x * blockDim.x + threadIdx.x;
  const size_t i = t * 4;
  const float* src;
  bf16* dst;
  size_t off;
  if (i < (size_t)3 * 1024 * 1024) {
    const int sel = (int)(i >> 20);
    src = sel == 0 ? Wq : (sel == 1 ? Wk : Wv);
    off = i - ((size_t)sel << 20);
    dst = Wqkv + i;
  } else {
    src = Wo;
    off = i - ((size_t)3 << 20);
    dst = WoB + off;
  }
  const f32x4 v = *(const f32x4*)(src + off);
  bf16x4 o;
  o[0] = (bf16)v[0];
  o[1] = (bf16)v[1];
  o[2] = (bf16)v[2];
  o[3] = (bf16)v[3];
  *(bf16x4*)dst = o;
}

// ===================== shared 128x128 GEMM mainloop (A [M,K], B [N,K], K=1024)
__device__ __forceinline__ void gemm_tile_128(const bf16* __restrict__ A,
                                              const bf16* __restrict__ Bm,
                                              int tm, int tn, bf16* ldsA, bf16* ldsB,
                                              f32x4 acc[4][4]) {
  const int tid = threadIdx.x;
  const int lane = tid & 63, wave = tid >> 6;
  const int wm = wave >> 1, wn = wave & 1;
  const int rl = lane & 15, quad = lane >> 4;
  const int sw = swz4(rl);
  int r0[2], c0[2], ld0[2];
#pragma unroll
  for (int j = 0; j < 2; ++j) {
    const int chunk = wave * 2 + j;
    const int o = chunk * 1024 + lane * 16;  // physical byte offset in 8KB tile
    const int r = o >> 6;                    // row (64B rows)
    r0[j] = r;
    c0[j] = (((o >> 4) & 3) ^ swz4(r)) * 8;  // logical element col (XOR swizzle)
    ld0[j] = chunk * 1024;                   // wave-uniform LDS window base
  }
  for (int kt = 0; kt < 1024; kt += 32) {
#pragma unroll
    for (int j = 0; j < 2; ++j) {
      gld16(A + (size_t)(tm + r0[j]) * 1024 + kt + c0[j], (char*)ldsA + ld0[j]);
      gld16(Bm + (size_t)(tn + r0[j]) * 1024 + kt + c0[j], (char*)ldsB + ld0[j]);
    }
    __syncthreads();
    bf16x8 af[4], bfr[4];
#pragma unroll
    for (int i = 0; i < 4; ++i) {
      const int ra = wm * 64 + i * 16 + rl;
      af[i] = *(const bf16x8*)((const char*)ldsA + ra * 64 + ((quad ^ sw) * 16));
      const int rb = wn * 64 + i * 16 + rl;
      bfr[i] = *(const bf16x8*)((const char*)ldsB + rb * 64 + ((quad ^ sw) * 16));
    }
#pragma unroll
    for (int i = 0; i < 4; ++i)
#pragma unroll
      for (int j = 0; j < 4; ++j)
        acc[i][j] = __builtin_amdgcn_mfma_f32_16x16x32_bf16(af[i], bfr[j], acc[i][j], 0, 0, 0);
    __syncthreads();
  }
}

// ===================== QKV projection GEMM ==================================
__global__ __launch_bounds__(256, 2) void gemm_qkv_kernel(
    const bf16* __restrict__ xT, const bf16* __restrict__ Wqkv,
    const float* __restrict__ bq, const float* __restrict__ bk,
    const float* __restrict__ bv, bf16* __restrict__ Q, bf16* __restrict__ Kb,
    bf16* __restrict__ VT) {
  __shared__ bf16 ldsA[128 * 32], ldsB[128 * 32];
  const int tm = blockIdx.x * 128, tn = blockIdx.y * 128;
  f32x4 acc[4][4];
  const f32x4 z = {0.f, 0.f, 0.f, 0.f};
#pragma unroll
  for (int i = 0; i < 4; ++i)
#pragma unroll
    for (int j = 0; j < 4; ++j) acc[i][j] = z;
  gemm_tile_128(xT, Wqkv, tm, tn, ldsA, ldsB, acc);
  const int lane = threadIdx.x & 63, wave = threadIdx.x >> 6;
  const int wm = wave >> 1, wn = wave & 1;
  const int rl = lane & 15, quad = lane >> 4;
  // Q scale folds 1/sqrt(64) * log2(e) so attn uses raw 2^x
  const float QSCALE = 0.18033688011112042f;
#pragma unroll
  for (int j = 0; j < 4; ++j) {
    const int n = tn + wn * 64 + j * 16 + rl;  // 0..3071
    const int which = n >> 10;                 // uniform per block
    const int nl = n & 1023;
    const int h = nl >> 6, d = nl & 63;
    const float bias = (which == 0 ? bq : which == 1 ? bk : bv)[nl];
#pragma unroll
    for (int i = 0; i < 4; ++i) {
      const int m0 = tm + wm * 64 + i * 16 + quad * 4;
      const int b = m0 >> 11, s0 = m0 & 2047;
      const size_t bh = (size_t)(b * 16 + h);
      if (which == 2) {
        bf16x4 pk;
#pragma unroll
        for (int r = 0; r < 4; ++r) pk[r] = (bf16)(acc[i][j][r] + bias);
        *(bf16x4*)(VT + ((size_t)bh * 64 + d) * 2048 + s0) = pk;  // V^T packed
      } else {
#pragma unroll
        for (int r = 0; r < 4; ++r) {
          const float v = acc[i][j][r] + bias;
          const int s = s0 + r;
          if (which == 0)
            Q[(bh * 2048 + s) * 64 + d] = (bf16)(v * QSCALE);
          else
            Kb[(bh * 2048 + s) * 64 + d] = (bf16)v;
        }
      }
    }
  }
}

// ===================== flash attention ======================================
// grid (B*H, S/256): bh on x for XCD/L2 locality. 256 q/block, 64 q/wave.
// Q direct to VGPRs. K/V double-buffered LDS (32 KB total). S^T = K*Q^T
// (16x16x32). P^T = exp(S^T) stays in registers and feeds 16x16x16 PV MFMAs
// as the B operand (C-layout == B-layout for K=16). O^T epilogue: packed
// bf16x4 stores, per-lane scalar l (rcp).
__global__ __launch_bounds__(256, 2) void attn_kernel(const bf16* __restrict__ Q,
                                                      const bf16* __restrict__ Kb,
                                                      const bf16* __restrict__ VT,
                                                      bf16* __restrict__ AO) {
  __shared__ __align__(16) char smem[32768];
  char* ldsK = smem;          // 2 x 8 KB (double buffer)
  char* ldsV = smem + 16384;  // 2 x 8 KB (double buffer)
  const int tid = threadIdx.x;
  const int lane = tid & 63, wave = tid >> 6;
  const int rl = lane & 15, quad = lane >> 4;
  const int bh = blockIdx.x;
  const int q0 = blockIdx.y * 256;
  const bf16* Qb = Q + ((size_t)bh * 2048 + q0) * 64;
  const bf16* Kbb = Kb + (size_t)bh * 2048 * 64;
  const bf16* Vb = VT + (size_t)bh * 64 * 2048;
  // staging geometry (shared by K and V): 2 x 16B chunks per thread per buffer
  const int o0 = wave * 1024 + lane * 16, o1 = o0 + 4096;
  const int ra = o0 >> 7, rb = o1 >> 7;
  const int ca = (((o0 >> 4) & 7) ^ (ra & 7)) * 16;
  const int cb = (((o1 >> 4) & 7) ^ (rb & 7)) * 16;
  gld16((const char*)Kbb + (size_t)ra * 128 + ca, ldsK + wave * 1024);
  gld16((const char*)Kbb + (size_t)rb * 128 + cb, ldsK + wave * 1024 + 4096);
  gld16((const char*)Vb + (size_t)ra * 4096 + ca, ldsV + wave * 1024);
  gld16((const char*)Vb + (size_t)rb * 4096 + cb, ldsV + wave * 1024 + 4096);
  // Q fragments straight from global (read exactly once; aligned 16B)
  bf16x8 qf[4][2];
#pragma unroll
  for (int i = 0; i < 4; ++i)
#pragma unroll
    for (int ks = 0; ks < 2; ++ks)
      qf[i][ks] = *(const bf16x8*)(Qb + (wave * 64 + i * 16 + rl) * 64 + ks * 32 + quad * 8);
  f32x4 o_acc[4][4];  // [dt][qt] — O^T tiles: rows d, cols q
  f32x4 l4[4];        // per-lane quad-partial row sums, per q-tile
  const f32x4 z = {0.f, 0.f, 0.f, 0.f};
#pragma unroll
  for (int i = 0; i < 4; ++i) {
    l4[i] = z;
#pragma unroll
    for (int j = 0; j < 4; ++j) o_acc[i][j] = z;
  }
  int buf = 0;
  for (int kt = 0; kt < 2048; kt += 64, buf ^= 1) {
    __syncthreads();  // K/V[buf] landed (vmcnt drain); buf^1 free for prefetch
    if (kt + 64 < 2048) {
      const int nb = (buf ^ 1) * 8192;
      gld16((const char*)Kbb + (size_t)(kt + 64 + ra) * 128 + ca, ldsK + nb + wave * 1024);
      gld16((const char*)Kbb + (size_t)(kt + 64 + rb) * 128 + cb,
            ldsK + nb + wave * 1024 + 4096);
      gld16((const char*)Vb + (size_t)ra * 4096 + (size_t)(kt + 64) * 2 + ca,
            ldsV + nb + wave * 1024);
      gld16((const char*)Vb + (size_t)rb * 4096 + (size_t)(kt + 64) * 2 + cb,
            ldsV + nb + wave * 1024 + 4096);
    }
    // S^T = K Q^T per key-row-tile jk, then exp+cvt: P^T fragments in regs.
    s16x4 pb[4][4];  // [jk=key16-step][qt] — B operand of 16x16x16 (k=quad*4+r)
#pragma unroll
    for (int jk = 0; jk < 4; ++jk) {
      f32x4 sacc[4];
#pragma unroll
      for (int i = 0; i < 4; ++i) sacc[i] = z;
#pragma unroll
      for (int ks = 0; ks < 2; ++ks) {
        const bf16x8 kf = *(const bf16x8*)(ldsK + buf * 8192 + (jk * 16 + rl) * 128 +
                                           (((ks * 4 + quad) ^ (rl & 7)) * 16));
#pragma unroll
        for (int i = 0; i < 4; ++i)
          sacc[i] =
              __builtin_amdgcn_mfma_f32_16x16x32_bf16(kf, qf[i][ks], sacc[i], 0, 0, 0);
      }
#pragma unroll
      for (int i = 0; i < 4; ++i) {
        f32x4 e;
#pragma unroll
        for (int r = 0; r < 4; ++r) e[r] = exp2_fast(sacc[i][r]);
        l4[i] += e;
        bf16x4 pk;
#pragma unroll
        for (int r = 0; r < 4; ++r) pk[r] = (bf16)e[r];
        pb[jk][i] = __builtin_bit_cast(s16x4, pk);
      }
    }
    // O^T += V^T P^T : A = V^T b64 fragments (4 keys/lane), B = pb (registers)
#pragma unroll
    for (int ki = 0; ki < 4; ++ki) {
#pragma unroll
      for (int dt = 0; dt < 4; ++dt) {
        const s16x4 vf = *(const s16x4*)(ldsV + buf * 8192 + (dt * 16 + rl) * 128 +
                                         (((ki * 2 + (quad >> 1)) ^ (rl & 7)) * 16) +
                                         (quad & 1) * 8);
#pragma unroll
        for (int qt = 0; qt < 4; ++qt)
          o_acc[dt][qt] = __builtin_amdgcn_mfma_f32_16x16x16bf16_1k(vf, pb[ki][qt],
                                                                    o_acc[dt][qt], 0, 0, 0);
      }
    }
  }
  // epilogue: l = butterfly over quads; O^T C-layout -> 4 consecutive d per lane
  const int b = bh >> 4, h = bh & 15;
#pragma unroll
  for (int qt = 0; qt < 4; ++qt) {
    float s = l4[qt][0] + l4[qt][1] + l4[qt][2] + l4[qt][3];
    s += __shfl_xor(s, 16);
    s += __shfl_xor(s, 32);
    const float linv = __builtin_amdgcn_rcpf(s);
    const size_t row = ((size_t)b * 2048 + q0 + wave * 64 + qt * 16 + rl) * 1024;
#pragma unroll
    for (int dt = 0; dt < 4; ++dt) {
      bf16x4 ov;
#pragma unroll
      for (int r = 0; r < 4; ++r) ov[r] = (bf16)(o_acc[dt][qt][r] * linv);
      *(bf16x4*)(AO + row + h * 64 + dt * 16 + quad * 4) = ov;
    }
  }
}

// ===================== output projection GEMM (transposed fp32 store) =======
__global__ __launch_bounds__(256, 2) void gemm_out_kernel(const bf16* __restrict__ AO,
                                                          const bf16* __restrict__ WoB,
                                                          const float* __restrict__ bo,
                                                          float* __restrict__ out) {
  __shared__ bf16 ldsA[128 * 32], ldsB[128 * 32];
  const int tm = blockIdx.x * 128, tn = blockIdx.y * 128;
  f32x4 acc[4][4];
  const f32x4 z = {0.f, 0.f, 0.f, 0.f};
#pragma unroll
  for (int i = 0; i < 4; ++i)
#pragma unroll
    for (int j = 0; j < 4; ++j) acc[i][j] = z;
  gemm_tile_128(AO, WoB, tm, tn, ldsA, ldsB, acc);
  const int lane = threadIdx.x & 63, wave = threadIdx.x >> 6;
  const int wm = wave >> 1, wn = wave & 1;
  const int rl = lane & 15, quad = lane >> 4;
#pragma unroll
  for (int j = 0; j < 4; ++j) {
    const int n = tn + wn * 64 + j * 16 + rl;  // = d
    const float bias = bo[n];
#pragma unroll
    for (int i = 0; i < 4; ++i) {
      const int m0 = tm + wm * 64 + i * 16 + quad * 4;
      const int b = m0 >> 11, s = m0 & 2047;
      f32x4 v = acc[i][j];
      v[0] += bias;
      v[1] += bias;
      v[2] += bias;
      v[3] += bias;
      *(f32x4*)(out + ((size_t)(b * 1024 + n)) * 2048 + s) = v;
    }
  }
}

extern "C" void kernel_launch(void* const* d_in, const int* in_sizes, int n_in,
                              void* d_out, int out_size, void* d_ws, size_t ws_size,
                              hipStream_t stream) {
  const float* x = (const float*)d_in[0];
  const float* Wq = (const float*)d_in[1];
  const float* bq = (const float*)d_in[2];
  const float* Wk = (const float*)d_in[3];
  const float* bk = (const float*)d_in[4];
  const float* Wv = (const float*)d_in[5];
  const float* bv = (const float*)d_in[6];
  const float* Wo = (const float*)d_in[7];
  const float* bo = (const float*)d_in[8];
  float* out = (float*)d_out;

  char* p = (char*)d_ws;
  bf16* xT = (bf16*)p;
  p += (size_t)NM * ND * 2;  // 16 MiB
  bf16* Wqkv = (bf16*)p;
  p += (size_t)3 * ND * ND * 2;  // 6 MiB
  bf16* WoB = (bf16*)p;
  p += (size_t)ND * ND * 2;  // 2 MiB
  bf16* Qb = (bf16*)p;
  p += (size_t)NM * ND * 2;
  bf16* Kbf = (bf16*)p;
  p += (size_t)NM * ND * 2;
  bf16* VTb = (bf16*)p;
  p += (size_t)NM * ND * 2;
  bf16* AO = xT;  // alias: xT fully consumed by gemm_qkv before attn writes AO

  prep_x_kernel<<<dim3(NS / 32, ND / 32, NB), dim3(32, 8), 0, stream>>>(x, xT);
  prep_w_kernel<<<dim3(4096), dim3(256), 0, stream>>>(Wq, Wk, Wv, Wo, Wqkv, WoB);
  gemm_qkv_kernel<<<dim3(NM / 128, 3072 / 128), dim3(256), 0, stream>>>(
      xT, Wqkv, bq, bk, bv, Qb, Kbf, VTb);
  attn_kernel<<<dim3(NB * NH, NS / 256), dim3(256), 0, stream>>>(Qb, Kbf, VTb, AO);
  gemm_out_kernel<<<dim3(NM / 128, ND / 128), dim3(256), 0, stream>>>(AO, WoB, bo, out);
}